// Round 6
// baseline (3552.122 us; speedup 1.0000x reference)
//
#include <hip/hip_runtime.h>
#include <math.h>

// Batched exact Hungarian (Jonker-Volgenant), bit-exact replica of the JAX/
// numpy reference decisions. One wave per batch; lane l owns CONTIGUOUS
// columns j = 4l..4l+3 (1-based jj = 4l+k+1): "lowest jj" tie-break ==
// lowest-k-locally then lowest-lane (ballot+ffs) == jnp.argmin first-occur.
//
// Round-6: VALU-issue-bound (220cy/iter == ~110 slots x 2cy). Pack the
// mul/sub/add arithmetic as float2 -> v_pk_{add,mul}_f32 (2 IEEE ops per
// slot, bitwise identical per half; fp contract(off) prevents pk_fma).
// Columns paired: P0=(k0,k1), P1=(k2,k3). sqrtf stays scalar+IEEE (the
// correctly-rounded sequence is what keeps absmax==0). Mark-used is now a
// wave-uniform switch on kk (scalar-pipe branches). min/way update uses
// cmp+2 cndmask == reference's where(upd,...) exactly.
//
// Output dtype: harness reads d_out as float32; col4row stored as floats.

#define NB   32
#define NN   256
#define ND   4
#define NPT  4
#define INFV 1e9f

typedef float v2f __attribute__((ext_vector_type(2)));

__device__ __forceinline__ float wave_min_bcast(float x) {
    // full 64-lane min; returns broadcast value (via readlane 63).
    int inf = __float_as_int(INFV);
    int t;
    t = __builtin_amdgcn_update_dpp(inf, __float_as_int(x), 0x111, 0xF, 0xF, false); // row_shr:1
    x = fminf(x, __int_as_float(t));
    t = __builtin_amdgcn_update_dpp(inf, __float_as_int(x), 0x112, 0xF, 0xF, false); // row_shr:2
    x = fminf(x, __int_as_float(t));
    t = __builtin_amdgcn_update_dpp(inf, __float_as_int(x), 0x114, 0xF, 0xF, false); // row_shr:4
    x = fminf(x, __int_as_float(t));
    t = __builtin_amdgcn_update_dpp(inf, __float_as_int(x), 0x118, 0xF, 0xF, false); // row_shr:8
    x = fminf(x, __int_as_float(t));
    t = __builtin_amdgcn_update_dpp(inf, __float_as_int(x), 0x142, 0xF, 0xF, false); // row_bcast:15
    x = fminf(x, __int_as_float(t));
    t = __builtin_amdgcn_update_dpp(inf, __float_as_int(x), 0x143, 0xF, 0xF, false); // row_bcast:31
    x = fminf(x, __int_as_float(t));
    return __int_as_float(__builtin_amdgcn_readlane(__float_as_int(x), 63));
}

__device__ __forceinline__ float readlane_f(float v, int lane) {
    return __int_as_float(__builtin_amdgcn_readlane(__float_as_int(v), lane));
}

__global__ __launch_bounds__(64) void hungarian_kernel(
    const float* __restrict__ pred, const float* __restrict__ gt,
    float* __restrict__ out)
{
#pragma clang fp contract(off)
    const int b    = blockIdx.x;
    const int lane = threadIdx.x;

    __shared__ float s_pred[NN][ND];   // pred points, 16B rows
    __shared__ float s_u[NN + 1];      // row potentials (1-based)
    __shared__ int   s_p[NN + 1];      // p[jj] = matched row (1-based)
    __shared__ int   s_way[NN];        // way, swizzled: [k*64 + lane]

    const float* pb = pred + (size_t)b * NN * ND;
    const float* gb = gt   + (size_t)b * NN * ND;

    #pragma unroll
    for (int k = 0; k < NPT; ++k) {
        int idx = lane + 64 * k;
        float4 pv = ((const float4*)pb)[idx];
        *(float4*)&s_pred[idx][0] = pv;
    }
    // gt coords for owned columns, paired: pair p holds (k=2p, k=2p+1)
    v2f gX[2], gY[2], gZ[2], gW[2];
    #pragma unroll
    for (int p = 0; p < 2; ++p) {
        float4 a = ((const float4*)gb)[4 * lane + 2 * p];
        float4 c = ((const float4*)gb)[4 * lane + 2 * p + 1];
        gX[p] = (v2f){a.x, c.x}; gY[p] = (v2f){a.y, c.y};
        gZ[p] = (v2f){a.z, c.z}; gW[p] = (v2f){a.w, c.w};
    }
    #pragma unroll
    for (int k = 0; k < NPT; ++k) {
        int jj = lane + 64 * k;
        s_u[jj] = 0.f; s_p[jj] = 0;
    }
    if (lane == 0) { s_u[NN] = 0.f; s_p[NN] = 0; }
    v2f v2_[2]; int pl[NPT];
    v2_[0] = (v2f){0.f, 0.f}; v2_[1] = (v2f){0.f, 0.f};
    #pragma unroll
    for (int k = 0; k < NPT; ++k) pl[k] = 0;
    const float FINF = __int_as_float(0x7f800000);
    __syncthreads();

    for (int i = 1; i <= NN; ++i) {
        if (lane == 0) s_p[0] = i;
        v2f minv2[2], uacc2[2], usedf2[2], used01_2[2];
        int wayr[NPT];
        #pragma unroll
        for (int p = 0; p < 2; ++p) {
            minv2[p] = (v2f){INFV, INFV}; uacc2[p] = (v2f){0.f, 0.f};
            usedf2[p] = (v2f){0.f, 0.f};  used01_2[p] = (v2f){0.f, 0.f};
        }
        wayr[0] = wayr[1] = wayr[2] = wayr[3] = 0;
        float u_i = 0.f;
        int   j1  = 0;
        float ui  = 0.f;
        float4 pr = *(const float4*)&s_pred[i - 1][0];
        int   i0n = i;

        for (int it = 0; it < NN + 2; ++it) {
            // mark column j1 used (wave-uniform kk/owner-lane -> scalar branch)
            if (j1 > 0) {
                int jm1 = j1 - 1;
                int kk  = jm1 & 3;
                bool own = (jm1 >> 2) == lane;
                int p = kk >> 1, h = kk & 1;
                if (h == 0) {
                    usedf2[p].x  = own ? FINF : usedf2[p].x;
                    used01_2[p].x = own ? 1.0f : used01_2[p].x;
                    uacc2[p].x   = own ? ui   : uacc2[p].x;
                } else {
                    usedf2[p].y  = own ? FINF : usedf2[p].y;
                    used01_2[p].y = own ? 1.0f : used01_2[p].y;
                    uacc2[p].y   = own ? ui   : uacc2[p].y;
                }
            }
            // packed scan: per pair, v_pk arithmetic; per-half rounding ==
            // reference's per-column scalar sequence exactly
            v2f m2[2];
            #pragma unroll
            for (int p = 0; p < 2; ++p) {
                v2f dx = pr.x - gX[p];          // pk_sub (sgpr broadcast)
                v2f dy = pr.y - gY[p];
                v2f dz = pr.z - gZ[p];
                v2f dw = pr.w - gW[p];
                v2f ss = dx * dx;
                ss = ss + dy * dy;              // contract(off): mul then add
                ss = ss + dz * dz;
                ss = ss + dw * dw;
                v2f sq = (v2f){sqrtf(ss.x), sqrtf(ss.y)};   // IEEE sqrt (exact)
                v2f cur = ((sq - ui) - v2_[p]) + usedf2[p]; // +0 exact / +inf gates
                // upd = cur < minv; minv = where(upd,cur,minv); way likewise
                bool u0 = cur.x < minv2[p].x;
                bool u1 = cur.y < minv2[p].y;
                minv2[p].x = u0 ? cur.x : minv2[p].x;
                minv2[p].y = u1 ? cur.y : minv2[p].y;
                wayr[2 * p]     = u0 ? j1 : wayr[2 * p];
                wayr[2 * p + 1] = u1 ? j1 : wayr[2 * p + 1];
                m2[p] = minv2[p] + usedf2[p];   // argmin mask (inf for used)
            }
            // local argmin, first-occurrence order k=0,1,2,3
            float best = m2[0].x; int bestk = 0;
            if (m2[0].y < best) { best = m2[0].y; bestk = 1; }
            if (m2[1].x < best) { best = m2[1].x; bestk = 2; }
            if (m2[1].y < best) { best = m2[1].y; bestk = 3; }
            int psel = pl[0];
            psel = (bestk == 1) ? pl[1] : psel;
            psel = (bestk == 2) ? pl[2] : psel;
            psel = (bestk == 3) ? pl[3] : psel;
            // speculative prefetch of candidate row's u/pred
            int pidx = (psel > 0) ? (psel - 1) : 0;
            float  u_spec = s_u[psel];
            float4 p_spec = *(const float4*)&s_pred[pidx][0];
            int code_local = (4 * lane + bestk + 1) | (psel << 12);
            // wave argmin: value min via DPP; owner = lowest lane at min
            const float gmin = wave_min_bcast(best);
            unsigned long long msk = __ballot(best == gmin);
            int owner = __ffsll(msk) - 1;
            int code  = __builtin_amdgcn_readlane(code_local, owner);
            int j1n   = code & 0xFFF;
            i0n       = code >> 12;
            // packed potential updates (delta = gmin), reference sequence:
            // du = delta*used01 (delta or 0, exact); v-=du; minv-=(delta-du);
            // uacc+=du
            const float delta = gmin;
            #pragma unroll
            for (int p = 0; p < 2; ++p) {
                v2f du = delta * used01_2[p];
                v2_[p]   = v2_[p] - du;
                minv2[p] = minv2[p] - (delta - du);
                uacc2[p] = uacc2[p] + du;
            }
            u_i += delta;
            j1 = j1n;
            if (i0n == 0) break;
            ui   = readlane_f(u_spec, owner);
            pr.x = readlane_f(p_spec.x, owner);
            pr.y = readlane_f(p_spec.y, owner);
            pr.z = readlane_f(p_spec.z, owner);
            pr.w = readlane_f(p_spec.w, owner);
        }

        // flush way registers to LDS (stride-1 per k, conflict-free)
        #pragma unroll
        for (int k = 0; k < NPT; ++k) s_way[(k << 6) + lane] = wayr[k];
        __syncthreads();
        // write back u for used columns + current row (pl pre-augment)
        if (used01_2[0].x != 0.f) s_u[pl[0]] = uacc2[0].x;
        if (used01_2[0].y != 0.f) s_u[pl[1]] = uacc2[0].y;
        if (used01_2[1].x != 0.f) s_u[pl[2]] = uacc2[1].x;
        if (used01_2[1].y != 0.f) s_u[pl[3]] = uacc2[1].y;
        if (lane == 0) s_u[i] = u_i;
        // augment along way chain (uniform walk; owners update pl)
        int j = j1;
        while (j != 0) {
            int jm1 = j - 1;
            int jp  = s_way[((jm1 & 3) << 6) + (jm1 >> 2)];
            int val = s_p[jp];
            if (lane == 0) s_p[j] = val;
            bool own = (jm1 >> 2) == lane;
            int  kk  = jm1 & 3;
            #pragma unroll
            for (int k = 0; k < NPT; ++k)
                pl[k] = (own && kk == k) ? val : pl[k];
            j = jp;
        }
        __syncthreads();
    }

    // outputs (float32): col4row[b][r-1] = j ; total_cost[b]
    float tot = 0.f;
    #pragma unroll
    for (int k = 0; k < NPT; ++k) {
        int p = k >> 1, h = k & 1;
        float gxk = h ? gX[p].y : gX[p].x;
        float gyk = h ? gY[p].y : gY[p].x;
        float gzk = h ? gZ[p].y : gZ[p].x;
        float gwk = h ? gW[p].y : gW[p].x;
        int j = 4 * lane + k;
        int r = pl[k];                        // 1-based matched row
        out[b * NN + (r - 1)] = (float)j;
        float4 p4 = *(const float4*)&s_pred[r - 1][0];
        float dx = p4.x - gxk, dy = p4.y - gyk;
        float dz = p4.z - gzk, dw = p4.w - gwk;
        tot += sqrtf(dx * dx + dy * dy + dz * dz + dw * dw);
    }
    for (int off = 32; off; off >>= 1) tot += __shfl_xor(tot, off);
    if (lane == 0) out[NB * NN + b] = tot;
}

extern "C" void kernel_launch(void* const* d_in, const int* in_sizes, int n_in,
                              void* d_out, int out_size, void* d_ws, size_t ws_size,
                              hipStream_t stream) {
    const float* pred = (const float*)d_in[0];
    const float* gt   = (const float*)d_in[1];
    float* out = (float*)d_out;
    hipLaunchKernelGGL(hungarian_kernel, dim3(NB), dim3(64), 0, stream,
                       pred, gt, out);
}

// Round 7
// 3178.528 us; speedup vs baseline: 1.1175x; 1.1175x over previous
//
#include <hip/hip_runtime.h>
#include <math.h>

// Batched exact Hungarian (Jonker-Volgenant), bit-exact replica of the JAX/
// numpy reference decisions. One wave per batch; lane l owns CONTIGUOUS
// columns j = 4l..4l+3 (1-based jj = 4l+k+1): "lowest jj" tie-break ==
// lowest-k-locally (tree, prefer-left) then lowest-lane (ballot+ffs).
//
// Round-7 (latency-chain surgery; round-6 showed we're dependency-bound,
// not issue-bound -- busy-CU VALU issue only ~14% of cycles):
//  - per-row precomputed codes (jj | pl<<12); 2-level tree argmin; psel
//    comes from code_local>>12 (no separate select chain)
//  - 5-step min3 DPP wave reduce (3->9->16 within row, bcast15, bcast31)
//  - mark-used moved to iteration tail (uniform kk if-chain), sets
//    minv[kk]=+inf so argmin reads minv directly (no +usedf add)
//  - speculative per-lane prefetch of candidate row's u/pred kept (r5)
//  - all float sequences identical to reference (x+0.0f / x-0 identities,
//    +inf gating; used01 mul trick) => absmax 0.0 preserved
//
// Output dtype: harness reads d_out as float32; col4row stored as floats.

#define NB   32
#define NN   256
#define ND   4
#define NPT  4
#define INFV 1e9f

__device__ __forceinline__ float wave_min_bcast(float x) {
    // 64-lane min in 5 dependent steps; fill=1e9 never wins (real vals < 1e3).
    const int fill = __float_as_int(INFV);
    int a, c;
    a = __builtin_amdgcn_update_dpp(fill, __float_as_int(x), 0x111, 0xF, 0xF, false); // row_shr:1
    c = __builtin_amdgcn_update_dpp(fill, __float_as_int(x), 0x112, 0xF, 0xF, false); // row_shr:2
    x = fminf(x, fminf(__int_as_float(a), __int_as_float(c)));      // cover 3
    a = __builtin_amdgcn_update_dpp(fill, __float_as_int(x), 0x113, 0xF, 0xF, false); // row_shr:3
    c = __builtin_amdgcn_update_dpp(fill, __float_as_int(x), 0x116, 0xF, 0xF, false); // row_shr:6
    x = fminf(x, fminf(__int_as_float(a), __int_as_float(c)));      // cover 9
    a = __builtin_amdgcn_update_dpp(fill, __float_as_int(x), 0x117, 0xF, 0xF, false); // row_shr:7
    x = fminf(x, __int_as_float(a));                                // cover 16
    a = __builtin_amdgcn_update_dpp(fill, __float_as_int(x), 0x142, 0xF, 0xF, false); // row_bcast:15
    x = fminf(x, __int_as_float(a));
    a = __builtin_amdgcn_update_dpp(fill, __float_as_int(x), 0x143, 0xF, 0xF, false); // row_bcast:31
    x = fminf(x, __int_as_float(a));                                // lane63 = global
    return __int_as_float(__builtin_amdgcn_readlane(__float_as_int(x), 63));
}

__device__ __forceinline__ float readlane_f(float v, int lane) {
    return __int_as_float(__builtin_amdgcn_readlane(__float_as_int(v), lane));
}

__global__ __launch_bounds__(64) void hungarian_kernel(
    const float* __restrict__ pred, const float* __restrict__ gt,
    float* __restrict__ out)
{
#pragma clang fp contract(off)
    const int b    = blockIdx.x;
    const int lane = threadIdx.x;

    __shared__ float s_pred[NN][ND];   // pred points, 16B rows
    __shared__ float s_u[NN + 1];      // row potentials (1-based)
    __shared__ int   s_p[NN + 1];      // p[jj] = matched row (1-based)
    __shared__ int   s_way[NN];        // way, swizzled: [k*64 + lane]

    const float* pb = pred + (size_t)b * NN * ND;
    const float* gb = gt   + (size_t)b * NN * ND;

    #pragma unroll
    for (int k = 0; k < NPT; ++k) {
        int idx = lane + 64 * k;
        float4 pv = ((const float4*)pb)[idx];
        *(float4*)&s_pred[idx][0] = pv;
    }
    float gx[NPT], gy[NPT], gz[NPT], gw[NPT];
    #pragma unroll
    for (int k = 0; k < NPT; ++k) {
        float4 gv = ((const float4*)gb)[4 * lane + k];
        gx[k] = gv.x; gy[k] = gv.y; gz[k] = gv.z; gw[k] = gv.w;
    }
    #pragma unroll
    for (int k = 0; k < NPT; ++k) {
        int jj = lane + 64 * k;
        s_u[jj] = 0.f; s_p[jj] = 0;
    }
    if (lane == 0) { s_u[NN] = 0.f; s_p[NN] = 0; }
    float v[NPT]; int pl[NPT];
    #pragma unroll
    for (int k = 0; k < NPT; ++k) { v[k] = 0.f; pl[k] = 0; }
    const float FINF = __int_as_float(0x7f800000);
    __syncthreads();

    for (int i = 1; i <= NN; ++i) {
        if (lane == 0) s_p[0] = i;
        int codes[NPT];                    // (jj | pl<<12), constant per row
        #pragma unroll
        for (int k = 0; k < NPT; ++k) codes[k] = (4 * lane + k + 1) | (pl[k] << 12);
        float minv[NPT], uacc[NPT], usedf[NPT], used01[NPT];
        int wayr[NPT];
        #pragma unroll
        for (int k = 0; k < NPT; ++k) {
            minv[k] = INFV; uacc[k] = 0.f; usedf[k] = 0.f; used01[k] = 0.f; wayr[k] = 0;
        }
        float u_i = 0.f;
        int   j1  = 0;
        float ui  = 0.f;                   // u[i] = 0 at row start
        float4 pr = *(const float4*)&s_pred[i - 1][0];
        int   i0n = i;

        for (int it = 0; it < NN + 2; ++it) {
            // scan owned columns (per-column arithmetic == reference exactly;
            // used columns gated to +inf via usedf; their minv is +inf)
            #pragma unroll
            for (int k = 0; k < NPT; ++k) {
                float dx = pr.x - gx[k], dy = pr.y - gy[k];
                float dz = pr.z - gz[k], dw = pr.w - gw[k];
                float ss = dx * dx + dy * dy + dz * dz + dw * dw;
                float cur = ((sqrtf(ss) - ui) - v[k]) + usedf[k];
                bool upd = cur < minv[k];
                minv[k] = upd ? cur : minv[k];
                wayr[k] = upd ? j1  : wayr[k];
            }
            // 2-level tree argmin (strict <, prefer-left == first-occurrence)
            bool s01 = minv[1] < minv[0];
            float v01 = s01 ? minv[1] : minv[0];
            int   c01 = s01 ? codes[1] : codes[0];
            bool s23 = minv[3] < minv[2];
            float v23 = s23 ? minv[3] : minv[2];
            int   c23 = s23 ? codes[3] : codes[2];
            bool sF  = v23 < v01;
            float best      = sF ? v23 : v01;
            int   code_local = sF ? c23 : c01;
            // speculative prefetch of local candidate row's u/pred
            int psel = code_local >> 12;
            int pidx = (psel > 0) ? psel - 1 : 0;
            float  u_spec = s_u[psel];
            float4 p_spec = *(const float4*)&s_pred[pidx][0];
            // wave argmin: value min via DPP; owner = lowest lane at min
            const float gmin = wave_min_bcast(best);
            unsigned long long msk = __ballot(best == gmin);
            int owner = __ffsll(msk) - 1;
            int code  = __builtin_amdgcn_readlane(code_local, owner);
            int j1n   = code & 0xFFF;
            i0n       = code >> 12;
            // potential updates (delta = gmin), reference value sequence:
            // du = delta*used01 (delta or +0); v-=du (x-0=x exact);
            // minv = (minv-delta)+du (+0 identity; inf stays inf); uacc+=du
            const float delta = gmin;
            #pragma unroll
            for (int k = 0; k < NPT; ++k) {
                float du = delta * used01[k];
                v[k]    -= du;
                minv[k]  = (minv[k] - delta) + du;
                uacc[k] += du;
            }
            u_i += delta;
            j1 = j1n;
            if (i0n == 0) break;          // free column found (updates done)
            // pull winner's speculative values (broadcast via readlane)
            float ui_new = readlane_f(u_spec, owner);
            pr.x = readlane_f(p_spec.x, owner);
            pr.y = readlane_f(p_spec.y, owner);
            pr.z = readlane_f(p_spec.z, owner);
            pr.w = readlane_f(p_spec.w, owner);
            // mark j1n used (tail position == ref's head-of-next-iteration;
            // uacc base = u[i0n] original value == ui_new). kk is uniform.
            {
                int jm1 = j1n - 1;
                int kk  = jm1 & 3;
                bool own = (jm1 >> 2) == lane;
                if (kk == 0) {
                    usedf[0]  = own ? FINF : usedf[0];
                    minv[0]   = own ? FINF : minv[0];
                    used01[0] = own ? 1.f  : used01[0];
                    uacc[0]   = own ? ui_new : uacc[0];
                } else if (kk == 1) {
                    usedf[1]  = own ? FINF : usedf[1];
                    minv[1]   = own ? FINF : minv[1];
                    used01[1] = own ? 1.f  : used01[1];
                    uacc[1]   = own ? ui_new : uacc[1];
                } else if (kk == 2) {
                    usedf[2]  = own ? FINF : usedf[2];
                    minv[2]   = own ? FINF : minv[2];
                    used01[2] = own ? 1.f  : used01[2];
                    uacc[2]   = own ? ui_new : uacc[2];
                } else {
                    usedf[3]  = own ? FINF : usedf[3];
                    minv[3]   = own ? FINF : minv[3];
                    used01[3] = own ? 1.f  : used01[3];
                    uacc[3]   = own ? ui_new : uacc[3];
                }
            }
            ui = ui_new;
        }

        // flush way registers to LDS (stride-1 per k, conflict-free)
        #pragma unroll
        for (int k = 0; k < NPT; ++k) s_way[(k << 6) + lane] = wayr[k];
        __syncthreads();   // way/p0 writes visible before augment reads
        // write back u for used columns + current row (pl pre-augment)
        #pragma unroll
        for (int k = 0; k < NPT; ++k)
            if (used01[k] != 0.0f) s_u[pl[k]] = uacc[k];
        if (lane == 0) s_u[i] = u_i;
        // augment along way chain (uniform walk; owners update pl)
        int j = j1;
        while (j != 0) {
            int jm1 = j - 1;
            int jp  = s_way[((jm1 & 3) << 6) + (jm1 >> 2)];
            int val = s_p[jp];
            if (lane == 0) s_p[j] = val;
            bool own = (jm1 >> 2) == lane;
            int  kk  = jm1 & 3;
            #pragma unroll
            for (int k = 0; k < NPT; ++k)
                pl[k] = (own && kk == k) ? val : pl[k];
            j = jp;
        }
        __syncthreads();   // u/p writes visible before next row's spec reads
    }

    // outputs (float32): col4row[b][r-1] = j ; total_cost[b]
    float tot = 0.f;
    #pragma unroll
    for (int k = 0; k < NPT; ++k) {
        int j = 4 * lane + k;
        int r = pl[k];                        // 1-based matched row
        out[b * NN + (r - 1)] = (float)j;
        float4 p4 = *(const float4*)&s_pred[r - 1][0];
        float dx = p4.x - gx[k], dy = p4.y - gy[k];
        float dz = p4.z - gz[k], dw = p4.w - gw[k];
        tot += sqrtf(dx * dx + dy * dy + dz * dz + dw * dw);
    }
    for (int off = 32; off; off >>= 1) tot += __shfl_xor(tot, off);
    if (lane == 0) out[NB * NN + b] = tot;
}

extern "C" void kernel_launch(void* const* d_in, const int* in_sizes, int n_in,
                              void* d_out, int out_size, void* d_ws, size_t ws_size,
                              hipStream_t stream) {
    const float* pred = (const float*)d_in[0];
    const float* gt   = (const float*)d_in[1];
    float* out = (float*)d_out;
    hipLaunchKernelGGL(hungarian_kernel, dim3(NB), dim3(64), 0, stream,
                       pred, gt, out);
}

// Round 8
// 2255.662 us; speedup vs baseline: 1.5748x; 1.4091x over previous
//
#include <hip/hip_runtime.h>
#include <math.h>

// Batched exact Hungarian (Jonker-Volgenant). One wave per batch; lane l owns
// contiguous columns j = 4l..4l+3 (1-based jj = 4l+k+1): "lowest jj" tie-break
// == lowest-k-locally (tree, prefer-left) then lowest-lane (ballot+ffs), which
// matches jnp.argmin first-occurrence.
//
// Round-8 = round-5 champion base (2991us) + three surgical edits:
//  - RAW v_sqrt_f32 in the Dijkstra scan (<=1ulp). Outputs depend only on
//    the decision sequence; epilogue total_cost uses IEEE sqrtf so it
//    bit-matches the reference whenever col4row matches. (Deliberate,
//    risk-assessed deviation from bit-exact internal costs.)
//  - per-row hoisted codes (jj | pl<<12) + 2-level tree argmin; psel from
//    code_local>>12 (kills the 3-cndmask psel chain).
//  - 5-step min3 DPP wave reduce (HW-verified in round 7).
// Everything else identical to round 5: head-mark, speculative per-lane
// prefetch of the candidate row's u/pred + readlane pulls, register-
// accumulated u, way[] in registers flushed per row, 2 barriers per row.
//
// Output dtype: harness reads d_out as float32; col4row stored as floats.

#define NB   32
#define NN   256
#define ND   4
#define NPT  4
#define INFV 1e9f

#if __has_builtin(__builtin_amdgcn_sqrtf)
__device__ __forceinline__ float fast_sqrtf(float x) { return __builtin_amdgcn_sqrtf(x); }
#else
__device__ __forceinline__ float fast_sqrtf(float x) {
    float r; asm volatile("v_sqrt_f32 %0, %1" : "=v"(r) : "v"(x)); return r;
}
#endif

__device__ __forceinline__ float wave_min_bcast(float x) {
    // 64-lane min in 5 dependent steps (min3 ladder); fill=1e9 never wins.
    const int fill = __float_as_int(INFV);
    int a, c;
    a = __builtin_amdgcn_update_dpp(fill, __float_as_int(x), 0x111, 0xF, 0xF, false); // row_shr:1
    c = __builtin_amdgcn_update_dpp(fill, __float_as_int(x), 0x112, 0xF, 0xF, false); // row_shr:2
    x = fminf(x, fminf(__int_as_float(a), __int_as_float(c)));      // cover 3
    a = __builtin_amdgcn_update_dpp(fill, __float_as_int(x), 0x113, 0xF, 0xF, false); // row_shr:3
    c = __builtin_amdgcn_update_dpp(fill, __float_as_int(x), 0x116, 0xF, 0xF, false); // row_shr:6
    x = fminf(x, fminf(__int_as_float(a), __int_as_float(c)));      // cover 9
    a = __builtin_amdgcn_update_dpp(fill, __float_as_int(x), 0x117, 0xF, 0xF, false); // row_shr:7
    x = fminf(x, __int_as_float(a));                                // cover 16
    a = __builtin_amdgcn_update_dpp(fill, __float_as_int(x), 0x142, 0xF, 0xF, false); // row_bcast:15
    x = fminf(x, __int_as_float(a));
    a = __builtin_amdgcn_update_dpp(fill, __float_as_int(x), 0x143, 0xF, 0xF, false); // row_bcast:31
    x = fminf(x, __int_as_float(a));                                // lane63 = global
    return __int_as_float(__builtin_amdgcn_readlane(__float_as_int(x), 63));
}

__device__ __forceinline__ float readlane_f(float v, int lane) {
    return __int_as_float(__builtin_amdgcn_readlane(__float_as_int(v), lane));
}

__global__ __launch_bounds__(64) void hungarian_kernel(
    const float* __restrict__ pred, const float* __restrict__ gt,
    float* __restrict__ out)
{
#pragma clang fp contract(off)
    const int b    = blockIdx.x;
    const int lane = threadIdx.x;

    __shared__ float s_pred[NN][ND];   // pred points, 16B rows
    __shared__ float s_u[NN + 1];      // row potentials (1-based)
    __shared__ int   s_p[NN + 1];      // p[jj] = matched row (1-based)
    __shared__ int   s_way[NN];        // way, swizzled: [k*64 + lane]

    const float* pb = pred + (size_t)b * NN * ND;
    const float* gb = gt   + (size_t)b * NN * ND;

    #pragma unroll
    for (int k = 0; k < NPT; ++k) {
        int idx = lane + 64 * k;
        float4 pv = ((const float4*)pb)[idx];
        *(float4*)&s_pred[idx][0] = pv;
    }
    float gx[NPT], gy[NPT], gz[NPT], gw[NPT];
    #pragma unroll
    for (int k = 0; k < NPT; ++k) {
        float4 gv = ((const float4*)gb)[4 * lane + k];
        gx[k] = gv.x; gy[k] = gv.y; gz[k] = gv.z; gw[k] = gv.w;
    }
    #pragma unroll
    for (int k = 0; k < NPT; ++k) {
        int jj = lane + 64 * k;
        s_u[jj] = 0.f; s_p[jj] = 0;
    }
    if (lane == 0) { s_u[NN] = 0.f; s_p[NN] = 0; }
    float v[NPT]; int pl[NPT];
    #pragma unroll
    for (int k = 0; k < NPT; ++k) { v[k] = 0.f; pl[k] = 0; }
    const float FINF = __int_as_float(0x7f800000);
    __syncthreads();

    for (int i = 1; i <= NN; ++i) {
        if (lane == 0) s_p[0] = i;
        int codes[NPT];                    // (jj | pl<<12), constant per row
        #pragma unroll
        for (int k = 0; k < NPT; ++k) codes[k] = (4 * lane + k + 1) | (pl[k] << 12);
        float minv[NPT], uacc[NPT], usedf[NPT], used01[NPT];
        int   wayr[NPT];
        #pragma unroll
        for (int k = 0; k < NPT; ++k) {
            minv[k] = INFV; uacc[k] = 0.f; usedf[k] = 0.f; used01[k] = 0.f; wayr[k] = 0;
        }
        float u_i = 0.f;
        int   j1  = 0;
        float ui  = 0.f;                          // u[i]=0 at row start
        float4 pr = *(const float4*)&s_pred[i - 1][0];
        int   i0n = i;

        for (int it = 0; it < NN + 2; ++it) {
            // mark column j1 as used (owner lane), snapshot its row's u (= ui)
            if (j1 > 0) {
                int jm1 = j1 - 1;                 // wave-uniform scalar
                #pragma unroll
                for (int k = 0; k < NPT; ++k) {
                    bool hit = (4 * lane + k) == jm1;
                    usedf[k]  = hit ? FINF : usedf[k];
                    used01[k] = hit ? 1.0f : used01[k];
                    uacc[k]   = hit ? ui   : uacc[k];
                }
            }
            // scan owned columns; fast sqrt (<=1ulp) — decisions only
            float m[NPT];
            #pragma unroll
            for (int k = 0; k < NPT; ++k) {
                float dx = pr.x - gx[k], dy = pr.y - gy[k];
                float dz = pr.z - gz[k], dw = pr.w - gw[k];
                float ss = dx * dx + dy * dy + dz * dz + dw * dw;
                float cur = ((fast_sqrtf(ss) - ui) - v[k]) + usedf[k];
                float old = minv[k];
                minv[k] = fminf(old, cur);
                wayr[k] = (cur < old) ? j1 : wayr[k];
                m[k] = minv[k] + usedf[k];        // argmin mask (inf for used)
            }
            // 2-level tree argmin (strict <, prefer-left == first-occurrence)
            bool s01 = m[1] < m[0];
            float v01 = s01 ? m[1] : m[0];
            int   c01 = s01 ? codes[1] : codes[0];
            bool s23 = m[3] < m[2];
            float v23 = s23 ? m[3] : m[2];
            int   c23 = s23 ? codes[3] : codes[2];
            bool sF  = v23 < v01;
            float best       = sF ? v23 : v01;
            int   code_local = sF ? c23 : c01;
            // speculative prefetch of candidate row's u/pred
            int psel = code_local >> 12;
            int pidx = (psel > 0) ? (psel - 1) : 0;
            float  u_spec = s_u[psel];
            float4 p_spec = *(const float4*)&s_pred[pidx][0];
            // wave argmin: value min via DPP; owner = lowest lane at min
            const float gmin = wave_min_bcast(best);
            unsigned long long msk = __ballot(best == gmin);
            int owner = __ffsll(msk) - 1;
            int code  = __builtin_amdgcn_readlane(code_local, owner);
            int j1n   = code & 0xFFF;
            i0n       = code >> 12;
            // potential updates (delta = gmin):
            // du = delta*used01; v-=du; minv-=(delta-du); uacc+=du
            const float delta = gmin;
            #pragma unroll
            for (int k = 0; k < NPT; ++k) {
                float du = delta * used01[k];
                v[k]    -= du;
                minv[k] -= (delta - du);
                uacc[k] += du;
            }
            u_i += delta;
            j1 = j1n;
            if (i0n == 0) break;                  // free column (updates done)
            ui   = readlane_f(u_spec, owner);
            pr.x = readlane_f(p_spec.x, owner);
            pr.y = readlane_f(p_spec.y, owner);
            pr.z = readlane_f(p_spec.z, owner);
            pr.w = readlane_f(p_spec.w, owner);
        }

        // flush way registers to LDS (stride-1 per k, conflict-free)
        #pragma unroll
        for (int k = 0; k < NPT; ++k) s_way[(k << 6) + lane] = wayr[k];
        __syncthreads();   // way/p0 writes visible before augment reads
        // write back u for used columns + current row (pl still pre-augment)
        #pragma unroll
        for (int k = 0; k < NPT; ++k)
            if (used01[k] != 0.0f) s_u[pl[k]] = uacc[k];
        if (lane == 0) s_u[i] = u_i;
        // augment along way chain (uniform walk; owners update pl)
        int j = j1;
        while (j != 0) {
            int jm1 = j - 1;
            int jp  = s_way[((jm1 & 3) << 6) + (jm1 >> 2)];
            int val = s_p[jp];
            if (lane == 0) s_p[j] = val;
            bool own = (jm1 >> 2) == lane;
            int  kk  = jm1 & 3;
            #pragma unroll
            for (int k = 0; k < NPT; ++k)
                pl[k] = (own && kk == k) ? val : pl[k];
            j = jp;
        }
        __syncthreads();   // u/p writes visible before next row's spec reads
    }

    // outputs (float32): col4row[b][r-1] = j ; total_cost[b]
    // IEEE sqrtf here -> bit-matches reference given the same col4row.
    float tot = 0.f;
    #pragma unroll
    for (int k = 0; k < NPT; ++k) {
        int j = 4 * lane + k;
        int r = pl[k];                        // 1-based matched row
        out[b * NN + (r - 1)] = (float)j;
        float4 p4 = *(const float4*)&s_pred[r - 1][0];
        float dx = p4.x - gx[k], dy = p4.y - gy[k];
        float dz = p4.z - gz[k], dw = p4.w - gw[k];
        tot += sqrtf(dx * dx + dy * dy + dz * dz + dw * dw);
    }
    for (int off = 32; off; off >>= 1) tot += __shfl_xor(tot, off);
    if (lane == 0) out[NB * NN + b] = tot;
}

extern "C" void kernel_launch(void* const* d_in, const int* in_sizes, int n_in,
                              void* d_out, int out_size, void* d_ws, size_t ws_size,
                              hipStream_t stream) {
    const float* pred = (const float*)d_in[0];
    const float* gt   = (const float*)d_in[1];
    float* out = (float*)d_out;
    hipLaunchKernelGGL(hungarian_kernel, dim3(NB), dim3(64), 0, stream,
                       pred, gt, out);
}